// Round 1
// baseline (235.921 us; speedup 1.0000x reference)
//
#include <hip/hip_runtime.h>

// DenseGrid bilinear interpolation: 2M pts, 256x256 grid, 48 feats (f32).
// Output viewed as float4[N_PTS*12]; one thread per float4 chunk.
// Writes perfectly coalesced; codebook gathers hit L2/L3 (12.6 MB table).

#define N_PTS   2000000
#define RES     256
#define FEAT4   12           // FEAT_DIM / 4
#define TOTAL   (N_PTS * FEAT4)   // 24,000,000 float4 outputs

__global__ __launch_bounds__(256) void densegrid_bilerp_kernel(
    const float2* __restrict__ pts,
    const float4* __restrict__ cb,      // codebook as float4, row stride FEAT4
    float4* __restrict__ out)
{
    unsigned int tid = blockIdx.x * blockDim.x + threadIdx.x;
    if (tid >= (unsigned int)TOTAL) return;

    unsigned int p = tid / FEAT4;       // point index
    unsigned int c = tid % FEAT4;       // feature chunk index

    float2 pt = pts[p];
    float fx = pt.x * (float)(RES - 1);
    float fy = pt.y * (float)(RES - 1);

    int ix = (int)floorf(fx);
    ix = ix < 0 ? 0 : (ix > RES - 2 ? RES - 2 : ix);
    int iy = (int)floorf(fy);
    iy = iy < 0 ? 0 : (iy > RES - 2 ? RES - 2 : iy);

    float wx = fx - (float)ix;          // weights from CLIPPED x0 (matches ref)
    float wy = fy - (float)iy;

    int base = ix * RES + iy;
    const float4* r = cb + (size_t)base * FEAT4 + c;
    float4 f00 = r[0];
    float4 f01 = r[FEAT4];              // base + 1 (iy+1)
    float4 f10 = r[RES * FEAT4];        // base + res (ix+1)
    float4 f11 = r[RES * FEAT4 + FEAT4];

    float w00 = (1.0f - wx) * (1.0f - wy);
    float w01 = (1.0f - wx) * wy;
    float w10 = wx * (1.0f - wy);
    float w11 = wx * wy;

    float4 o;
    o.x = f00.x * w00 + f01.x * w01 + f10.x * w10 + f11.x * w11;
    o.y = f00.y * w00 + f01.y * w01 + f10.y * w10 + f11.y * w11;
    o.z = f00.z * w00 + f01.z * w01 + f10.z * w10 + f11.z * w11;
    o.w = f00.w * w00 + f01.w * w01 + f10.w * w10 + f11.w * w11;

    out[tid] = o;
}

extern "C" void kernel_launch(void* const* d_in, const int* in_sizes, int n_in,
                              void* d_out, int out_size, void* d_ws, size_t ws_size,
                              hipStream_t stream) {
    const float2* pts = (const float2*)d_in[0];
    const float4* cb  = (const float4*)d_in[1];
    float4* out       = (float4*)d_out;

    const int threads = 256;
    const int blocks  = (TOTAL + threads - 1) / threads;  // 93750
    densegrid_bilerp_kernel<<<blocks, threads, 0, stream>>>(pts, cb, out);
}

// Round 3
// 220.834 us; speedup vs baseline: 1.0683x; 1.0683x over previous
//
#include <hip/hip_runtime.h>

// DenseGrid bilinear interpolation: 2M pts, 256x256 grid, 48 feats (f32).
// Output viewed as f32x4[N_PTS*12]; one thread per float4 chunk.
// Writes perfectly coalesced and NONTEMPORAL (output is write-once,
// 384 MB > L3 — keep it out of L2/L3 so the 12.6 MB codebook stays cached).
// Use native clang ext_vector (not HIP_vector_type) — the nontemporal
// builtin only accepts scalar/native-vector pointees.

#define N_PTS   2000000
#define RES     256
#define FEAT4   12           // FEAT_DIM / 4
#define TOTAL   (N_PTS * FEAT4)   // 24,000,000 float4 outputs

typedef float f32x4 __attribute__((ext_vector_type(4)));
typedef float f32x2 __attribute__((ext_vector_type(2)));

__global__ __launch_bounds__(256) void densegrid_bilerp_kernel(
    const f32x2* __restrict__ pts,
    const f32x4* __restrict__ cb,       // codebook as float4, row stride FEAT4
    f32x4* __restrict__ out)
{
    unsigned int tid = blockIdx.x * blockDim.x + threadIdx.x;
    if (tid >= (unsigned int)TOTAL) return;

    unsigned int p = tid / FEAT4;       // point index
    unsigned int c = tid % FEAT4;       // feature chunk index

    f32x2 pt = pts[p];
    float fx = pt.x * (float)(RES - 1);
    float fy = pt.y * (float)(RES - 1);

    int ix = (int)floorf(fx);
    ix = ix < 0 ? 0 : (ix > RES - 2 ? RES - 2 : ix);
    int iy = (int)floorf(fy);
    iy = iy < 0 ? 0 : (iy > RES - 2 ? RES - 2 : iy);

    float wx = fx - (float)ix;          // weights from CLIPPED x0 (matches ref)
    float wy = fy - (float)iy;

    int base = ix * RES + iy;
    const f32x4* r = cb + (size_t)base * FEAT4 + c;
    f32x4 f00 = r[0];
    f32x4 f01 = r[FEAT4];               // base + 1 (iy+1)
    f32x4 f10 = r[RES * FEAT4];         // base + res (ix+1)
    f32x4 f11 = r[RES * FEAT4 + FEAT4];

    float w00 = (1.0f - wx) * (1.0f - wy);
    float w01 = (1.0f - wx) * wy;
    float w10 = wx * (1.0f - wy);
    float w11 = wx * wy;

    f32x4 o = f00 * w00 + f01 * w01 + f10 * w10 + f11 * w11;

    // Nontemporal: output is streaming write-once; keep it out of L2/L3.
    __builtin_nontemporal_store(o, &out[tid]);
}

extern "C" void kernel_launch(void* const* d_in, const int* in_sizes, int n_in,
                              void* d_out, int out_size, void* d_ws, size_t ws_size,
                              hipStream_t stream) {
    const f32x2* pts = (const f32x2*)d_in[0];
    const f32x4* cb  = (const f32x4*)d_in[1];
    f32x4* out       = (f32x4*)d_out;

    const int threads = 256;
    const int blocks  = (TOTAL + threads - 1) / threads;  // 93750
    densegrid_bilerp_kernel<<<blocks, threads, 0, stream>>>(pts, cb, out);
}